// Round 10
// baseline (463.449 us; speedup 1.0000x reference)
//
#include <hip/hip_runtime.h>
#include <hip/hip_bf16.h>
#include <hip/hip_fp16.h>

#define N_NODES 50000
#define N_EDGES 1600000
#define HIDDEN  128
#define EPS_C   0.3f
#define NWORDS  12500      // 50000 nodes, 4 u8 counters per u32 word
#define CHUNK   6250       // edges per histogram block; 256 chunks = 1.6M
#define NCHUNK  256

typedef _Float16 f16x8 __attribute__((ext_vector_type(8)));
typedef _Float16 f16x4 __attribute__((ext_vector_type(4)));
typedef float    f32x16 __attribute__((ext_vector_type(16)));

// ---------------- per-chunk LDS histograms (u8-packed), zero global atomics ----------------
// grid 512: blocks 0..255 count rows (deg), 256..511 count cols (cnt)
__global__ __launch_bounds__(256) void k_hist(const int* __restrict__ ei, unsigned int* __restrict__ part) {
    __shared__ unsigned int hist[NWORDS];   // 50 KB
    int b = blockIdx.x;
    int type  = b >> 8;
    int chunk = b & 255;
    const int* src = ei + (size_t)type * N_EDGES + (size_t)chunk * CHUNK;
    for (int i = threadIdx.x; i < NWORDS; i += 256) hist[i] = 0;
    __syncthreads();
    for (int i = threadIdx.x; i < CHUNK; i += 256) {
        int v = src[i];
        atomicAdd(&hist[v >> 2], 1u << ((v & 3) * 8));
    }
    __syncthreads();
    unsigned int* dst = part + ((size_t)type * NCHUNK + chunk) * NWORDS;
    for (int i = threadIdx.x; i < NWORDS; i += 256) dst[i] = hist[i];
}

// ---------------- reduce partials -> nd, cnt, and per-(chunk,col) u8 exclusive prefix ----------------
__global__ __launch_bounds__(256) void k_reduce(const unsigned int* __restrict__ part,
                                                float* __restrict__ nd, int* __restrict__ cnt,
                                                unsigned char* __restrict__ cntpre) {
    int w = blockIdx.x * 256 + threadIdx.x;
    if (w >= NWORDS) return;
    // deg (rows)
    unsigned int s0 = 0, s1 = 0, s2 = 0, s3 = 0;
    const unsigned int* dp = part + w;
    for (int b = 0; b < NCHUNK; ++b) {
        unsigned int v = dp[(size_t)b * NWORDS];
        s0 += v & 255u; s1 += (v >> 8) & 255u; s2 += (v >> 16) & 255u; s3 += v >> 24;
    }
    nd[4 * w + 0] = rsqrtf(fmaxf((float)s0, 1.f));
    nd[4 * w + 1] = rsqrtf(fmaxf((float)s1, 1.f));
    nd[4 * w + 2] = rsqrtf(fmaxf((float)s2, 1.f));
    nd[4 * w + 3] = rsqrtf(fmaxf((float)s3, 1.f));
    // cnt (cols) + u8 exclusive prefix per chunk (per-chunk per-node count << 255)
    const unsigned int* cp = part + (size_t)NCHUNK * NWORDS + w;
    unsigned int r0 = 0, r1 = 0, r2 = 0, r3 = 0;
    for (int b = 0; b < NCHUNK; ++b) {
        size_t o = (size_t)b * N_NODES + 4 * w;
        *(uchar4*)&cntpre[o] = make_uchar4((unsigned char)r0, (unsigned char)r1,
                                           (unsigned char)r2, (unsigned char)r3);
        unsigned int v = cp[(size_t)b * NWORDS];
        r0 += v & 255u; r1 += (v >> 8) & 255u; r2 += (v >> 16) & 255u; r3 += v >> 24;
    }
    cnt[4 * w + 0] = (int)r0;
    cnt[4 * w + 1] = (int)r1;
    cnt[4 * w + 2] = (int)r2;
    cnt[4 * w + 3] = (int)r3;
}

// ---------------- 3-kernel exclusive scan of cnt -> colptr ----------------
__global__ __launch_bounds__(256) void k_scan_a(const int* __restrict__ cnt,
                                                int* __restrict__ out, int* __restrict__ partials) {
    __shared__ int sh[256];
    int t = threadIdx.x;
    int base = blockIdx.x * 1024 + t * 4;
    int v0 = (base + 0 < N_NODES) ? cnt[base + 0] : 0;
    int v1 = (base + 1 < N_NODES) ? cnt[base + 1] : 0;
    int v2 = (base + 2 < N_NODES) ? cnt[base + 2] : 0;
    int v3 = (base + 3 < N_NODES) ? cnt[base + 3] : 0;
    int s = v0 + v1 + v2 + v3;
    sh[t] = s;
    __syncthreads();
    for (int off = 1; off < 256; off <<= 1) {
        int add = (t >= off) ? sh[t - off] : 0;
        __syncthreads();
        sh[t] += add;
        __syncthreads();
    }
    int excl = sh[t] - s;
    if (t == 255) partials[blockIdx.x] = sh[255];
    if (base + 0 < N_NODES) out[base + 0] = excl;
    if (base + 1 < N_NODES) out[base + 1] = excl + v0;
    if (base + 2 < N_NODES) out[base + 2] = excl + v0 + v1;
    if (base + 3 < N_NODES) out[base + 3] = excl + v0 + v1 + v2;
}

__global__ void k_scan_b(int* partials, int* colptr, int nb) {
    if (threadIdx.x == 0 && blockIdx.x == 0) {
        int run = 0;
        for (int i = 0; i < nb; ++i) { int t = partials[i]; partials[i] = run; run += t; }
        colptr[N_NODES] = run;   // == E
    }
}

__global__ void k_scan_c(int* __restrict__ colptr, const int* __restrict__ partials) {
    int i = blockIdx.x * blockDim.x + threadIdx.x;
    if (i >= N_NODES) return;
    colptr[i] += partials[i >> 10];
}

// ---------------- scatter via LDS rank, zero global atomics ----------------
__global__ __launch_bounds__(256) void k_scatter2(const int* __restrict__ ei, const int* __restrict__ colptr,
                                                  const unsigned char* __restrict__ cntpre,
                                                  int* __restrict__ csr) {
    __shared__ unsigned int rank[NWORDS];   // 50 KB
    int b = blockIdx.x;
    for (int i = threadIdx.x; i < NWORDS; i += 256) rank[i] = 0;
    __syncthreads();
    const int* rs = ei + (size_t)b * CHUNK;
    const int* cs = ei + N_EDGES + (size_t)b * CHUNK;
    const unsigned char* pre = cntpre + (size_t)b * N_NODES;
    for (int i = threadIdx.x; i < CHUNK; i += 256) {
        int r = rs[i];
        int c = cs[i];
        unsigned int old = atomicAdd(&rank[c >> 2], 1u << ((c & 3) * 8));
        unsigned int lr = (old >> ((c & 3) * 8)) & 255u;
        int pos = colptr[c] + (int)pre[c] + (int)lr;
        csr[pos] = r;
    }
}

// ---------------- fp32 -> fp16 convert (n4 = count of float4) ----------------
__global__ void k_cvt(const float4* __restrict__ src, __half2* __restrict__ dst, int n4) {
    int i = blockIdx.x * 256 + threadIdx.x;
    if (i >= n4) return;
    float4 v = src[i];
    dst[2 * i]     = __floats2half2_rn(v.x, v.y);
    dst[2 * i + 1] = __floats2half2_rn(v.z, v.w);
}

// ---------------- fp32 -> fp16 convert with zero-padding past n4src ----------------
__global__ void k_cvtw(const float4* __restrict__ src, __half2* __restrict__ dst, int n4src, int n4tot) {
    int i = blockIdx.x * 256 + threadIdx.x;
    if (i >= n4tot) return;
    if (i < n4src) {
        float4 v = src[i];
        dst[2 * i]     = __floats2half2_rn(v.x, v.y);
        dst[2 * i + 1] = __floats2half2_rn(v.z, v.w);
    } else {
        __half2 z = __floats2half2_rn(0.f, 0.f);
        dst[2 * i]     = z;
        dst[2 * i + 1] = z;
    }
}

// ---------------- GEMM1: h = relu(x @ W1^T + b1), LDS-staged fp16 MFMA, f16-only output ----------------
__global__ __launch_bounds__(256) void k_gemm1(const float* __restrict__ x, const _Float16* __restrict__ wh,
                                               const float* __restrict__ bias, _Float16* __restrict__ hb) {
    __shared__ _Float16 As[64 * 64];    // 8 KB, swizzled
    __shared__ _Float16 Bs[128 * 64];   // 16 KB, swizzled
    int t = threadIdx.x;
    int wave = t >> 6;
    int lane = t & 63;
    int lm   = lane & 31;
    int half = lane >> 5;
    int mstrip = wave & 1;
    int nstrip = wave >> 1;

    int m0  = blockIdx.x * 64;
    int wm0 = m0 + mstrip * 32;     // wave's M base
    int n0  = nstrip * 64;          // wave's N base

    int aidx[4], arow[4], ac4[4];
    int bidx, brow[4], bg[4];
#pragma unroll
    for (int i = 0; i < 4; ++i) {
        aidx[i] = i * 256 + t;
        arow[i] = aidx[i] >> 4;
        ac4[i]  = aidx[i] & 15;
        bidx    = i * 256 + t;
        brow[i] = bidx >> 3;
        bg[i]   = bidx & 7;
    }

    float4 pa[4];
    f16x8  pb[4];
#define LOAD_TILES(K0)                                                                    \
    {                                                                                     \
        _Pragma("unroll")                                                                 \
        for (int i = 0; i < 4; ++i) {                                                     \
            int gr = m0 + arow[i]; if (gr >= N_NODES) gr = N_NODES - 1;                   \
            pa[i] = *(const float4*)(x + (size_t)gr * 512 + (K0) + ac4[i] * 4);           \
            pb[i] = *(const f16x8*)(wh + (size_t)brow[i] * 512 + (K0) + bg[i] * 8);       \
        }                                                                                 \
    }

    f32x16 acc0, acc1;
#pragma unroll
    for (int i = 0; i < 16; ++i) { acc0[i] = 0.f; acc1[i] = 0.f; }

    int ar = mstrip * 32 + lm;
    int brA = n0 + lm;
    int brB = n0 + 32 + lm;

    LOAD_TILES(0);
    for (int k0 = 0; k0 < 512; k0 += 64) {
#pragma unroll
        for (int i = 0; i < 4; ++i) {
            f16x4 a;
            a[0] = (_Float16)pa[i].x; a[1] = (_Float16)pa[i].y;
            a[2] = (_Float16)pa[i].z; a[3] = (_Float16)pa[i].w;
            int g = ac4[i] >> 1;
            *(f16x4*)&As[arow[i] * 64 + (((g ^ (arow[i] & 7)) << 3)) + (ac4[i] & 1) * 4] = a;
            *(f16x8*)&Bs[brow[i] * 64 + ((bg[i] ^ (brow[i] & 7)) << 3)] = pb[i];
        }
        __syncthreads();
        if (k0 + 64 < 512) LOAD_TILES(k0 + 64);   // prefetch overlaps compute
#pragma unroll
        for (int kk = 0; kk < 4; ++kk) {
            int ag = kk * 2 + half;
            f16x8 av  = *(const f16x8*)&As[ar  * 64 + ((ag ^ (ar  & 7)) << 3)];
            f16x8 bv0 = *(const f16x8*)&Bs[brA * 64 + ((ag ^ (brA & 7)) << 3)];
            f16x8 bv1 = *(const f16x8*)&Bs[brB * 64 + ((ag ^ (brA & 7)) << 3)];
            acc0 = __builtin_amdgcn_mfma_f32_32x32x16_f16(av, bv0, acc0, 0, 0, 0);
            acc1 = __builtin_amdgcn_mfma_f32_32x32x16_f16(av, bv1, acc1, 0, 0, 0);
        }
        __syncthreads();
    }
#undef LOAD_TILES

    float bs0 = bias[n0 + lm];
    float bs1 = bias[n0 + 32 + lm];
#pragma unroll
    for (int reg = 0; reg < 16; ++reg) {
        int row = (reg & 3) + 8 * (reg >> 2) + 4 * half;
        int gm = wm0 + row;
        if (gm < N_NODES) {
            float v0 = fmaxf(acc0[reg] + bs0, 0.f);
            float v1 = fmaxf(acc1[reg] + bs1, 0.f);
            hb[(size_t)gm * HIDDEN + n0 + lm]      = (_Float16)v0;
            hb[(size_t)gm * HIDDEN + n0 + 32 + lm] = (_Float16)v1;
        }
    }
}

// ---------------- per-node gate dots (layer 0): dn = {h.w_r, nd}, dcb = h.w_c + gb ----------------
__global__ __launch_bounds__(256) void k_dot(const __half2* __restrict__ hb, const float* __restrict__ gw,
                                             const float* __restrict__ gb, const float* __restrict__ nd,
                                             int layer, float2* __restrict__ dn, float* __restrict__ dcb) {
    int node = blockIdx.x * 4 + (threadIdx.x >> 6);
    int lane = threadIdx.x & 63;
    if (node >= N_NODES) return;
    float2 wr = ((const float2*)(gw + layer * 256))[lane];
    float2 wc = ((const float2*)(gw + layer * 256 + 128))[lane];
    float2 hc = __half22float2(hb[(size_t)node * 64 + lane]);
    float a = hc.x * wr.x + hc.y * wr.y;
    float b = hc.x * wc.x + hc.y * wc.y;
#pragma unroll
    for (int off = 32; off >= 1; off >>= 1) {
        a += __shfl_xor(a, off, 64);
        b += __shfl_xor(b, off, 64);
    }
    if (lane == 0) {
        dn[node]  = make_float2(a, nd[node]);
        dcb[node] = b + gb[layer];
    }
}

// gate weight for one edge: tanh(dot_r + dc) * nd[r], computed wave-uniformly
__device__ __forceinline__ float gatew(float2 d, float dc) {
    float t = __expf(2.0f * (d.x + dc));      // saturates to inf / 0, no NaN below
    return (1.0f - 2.0f / (t + 1.0f)) * d.y;  // == tanh(.) * nd[r]
}

// ---------------- propagation with inline uniform gate: wave per node ----------------
// csr[p] / dn[r] are wave-uniform loads (scalar cache); gate math runs on uniform values;
// hb gathers use 32-bit voffsets (base + (r<<8 | lane<<2)). No LDS, no warr round-trip.
// Optional fused next-layer gate dot in the epilogue (double-buffered dn/dcb across layers).
__global__ __launch_bounds__(256) void k_prop(const __half2* __restrict__ hb, const __half2* __restrict__ rawh,
                                              const int* __restrict__ colptr, const int* __restrict__ csr,
                                              const float2* __restrict__ dn_in, const float* __restrict__ dcb_in,
                                              const float* __restrict__ nd,
                                              const float* __restrict__ gw_next, const float* __restrict__ gb_next,
                                              float2* __restrict__ dn_out, float* __restrict__ dcb_out,
                                              __half2* __restrict__ hbn) {
    int lane = threadIdx.x & 63;
    // wave-uniform node/beg/end in SGPRs
    int node = __builtin_amdgcn_readfirstlane(blockIdx.x * 4 + (threadIdx.x >> 6));
    int beg = __builtin_amdgcn_readfirstlane(colptr[node]);
    int end = __builtin_amdgcn_readfirstlane(colptr[node + 1]);
    float dc = dcb_in[node];
    const char* hbc = (const char*)hb;
    unsigned loff = (unsigned)(lane << 2);
    float acc0 = 0.f, acc1 = 0.f;
    int p = beg;
    for (; p + 8 <= end; p += 8) {
        int r0 = csr[p + 0], r1 = csr[p + 1], r2 = csr[p + 2], r3 = csr[p + 3];
        int r4 = csr[p + 4], r5 = csr[p + 5], r6 = csr[p + 6], r7 = csr[p + 7];
        // 8 independent gathers issue as soon as r's arrive (32-bit voffset addressing)
        __half2 v0 = *(const __half2*)(hbc + ((unsigned)(r0 << 8) + loff));
        __half2 v1 = *(const __half2*)(hbc + ((unsigned)(r1 << 8) + loff));
        __half2 v2 = *(const __half2*)(hbc + ((unsigned)(r2 << 8) + loff));
        __half2 v3 = *(const __half2*)(hbc + ((unsigned)(r3 << 8) + loff));
        __half2 v4 = *(const __half2*)(hbc + ((unsigned)(r4 << 8) + loff));
        __half2 v5 = *(const __half2*)(hbc + ((unsigned)(r5 << 8) + loff));
        __half2 v6 = *(const __half2*)(hbc + ((unsigned)(r6 << 8) + loff));
        __half2 v7 = *(const __half2*)(hbc + ((unsigned)(r7 << 8) + loff));
        // uniform gate inputs (400 KB dn table, L2-resident, broadcast loads)
        float2 d0 = dn_in[r0], d1 = dn_in[r1], d2 = dn_in[r2], d3 = dn_in[r3];
        float2 d4 = dn_in[r4], d5 = dn_in[r5], d6 = dn_in[r6], d7 = dn_in[r7];
        float w0 = gatew(d0, dc), w1 = gatew(d1, dc), w2 = gatew(d2, dc), w3 = gatew(d3, dc);
        float w4 = gatew(d4, dc), w5 = gatew(d5, dc), w6 = gatew(d6, dc), w7 = gatew(d7, dc);
        acc0 = fmaf(w0, __low2float(v0), acc0);  acc1 = fmaf(w0, __high2float(v0), acc1);
        acc0 = fmaf(w1, __low2float(v1), acc0);  acc1 = fmaf(w1, __high2float(v1), acc1);
        acc0 = fmaf(w2, __low2float(v2), acc0);  acc1 = fmaf(w2, __high2float(v2), acc1);
        acc0 = fmaf(w3, __low2float(v3), acc0);  acc1 = fmaf(w3, __high2float(v3), acc1);
        acc0 = fmaf(w4, __low2float(v4), acc0);  acc1 = fmaf(w4, __high2float(v4), acc1);
        acc0 = fmaf(w5, __low2float(v5), acc0);  acc1 = fmaf(w5, __high2float(v5), acc1);
        acc0 = fmaf(w6, __low2float(v6), acc0);  acc1 = fmaf(w6, __high2float(v6), acc1);
        acc0 = fmaf(w7, __low2float(v7), acc0);  acc1 = fmaf(w7, __high2float(v7), acc1);
    }
    for (; p < end; ++p) {
        int r = csr[p];
        __half2 v = *(const __half2*)(hbc + ((unsigned)(r << 8) + loff));
        float w = gatew(dn_in[r], dc);
        acc0 = fmaf(w, __low2float(v), acc0);
        acc1 = fmaf(w, __high2float(v), acc1);
    }
    float ndc = nd[node];
    float2 rw = __half22float2(rawh[(size_t)node * 64 + lane]);
    float2 o;
    o.x = fmaf(EPS_C, rw.x, ndc * acc0);
    o.y = fmaf(EPS_C, rw.y, ndc * acc1);
    hbn[(size_t)node * 64 + lane] = __floats2half2_rn(o.x, o.y);
    if (gw_next) {
        // fused next-layer gate dot -> double-buffered dn_out/dcb_out
        float2 wr = ((const float2*)gw_next)[lane];
        float2 wc = ((const float2*)(gw_next + 128))[lane];
        float a = o.x * wr.x + o.y * wr.y;
        float b = o.x * wc.x + o.y * wc.y;
#pragma unroll
        for (int off = 32; off >= 1; off >>= 1) {
            a += __shfl_xor(a, off, 64);
            b += __shfl_xor(b, off, 64);
        }
        if (lane == 0) {
            dn_out[node]  = make_float2(a, ndc);
            dcb_out[node] = b + gb_next[0];
        }
    }
}

// ---------------- output: logits = h @ W2^T + b2 via MFMA, log_softmax in epilogue ----------------
__global__ __launch_bounds__(256) void k_out(const _Float16* __restrict__ h16, const _Float16* __restrict__ w2h,
                                             const float* __restrict__ b2, float* __restrict__ out) {
    int wave = threadIdx.x >> 6;
    int lane = threadIdx.x & 63;
    int lm   = lane & 31;
    int half = lane >> 5;

    int wm0 = blockIdx.x * 128 + wave * 32;
    int m   = wm0 + lm;
    int mc  = (m < N_NODES) ? m : (N_NODES - 1);

    const _Float16* arow  = h16 + (size_t)mc * HIDDEN + half * 8;
    const _Float16* brow0 = w2h + (size_t)lm * HIDDEN + half * 8;
    const _Float16* brow1 = w2h + (size_t)(32 + lm) * HIDDEN + half * 8;

    f32x16 acc0, acc1;
#pragma unroll
    for (int i = 0; i < 16; ++i) { acc0[i] = 0.f; acc1[i] = 0.f; }

#pragma unroll
    for (int k0 = 0; k0 < 128; k0 += 16) {
        f16x8 av = *(const f16x8*)(arow  + k0);
        f16x8 b0 = *(const f16x8*)(brow0 + k0);
        f16x8 b1 = *(const f16x8*)(brow1 + k0);
        acc0 = __builtin_amdgcn_mfma_f32_32x32x16_f16(av, b0, acc0, 0, 0, 0);
        acc1 = __builtin_amdgcn_mfma_f32_32x32x16_f16(av, b1, acc1, 0, 0, 0);
    }

    float bj0 = b2[lm];
    float bj1 = (lm < 8) ? b2[32 + lm] : 0.f;

#pragma unroll
    for (int reg = 0; reg < 16; ++reg) {
        int row = (reg & 3) + 8 * (reg >> 2) + 4 * half;
        float v0 = acc0[reg] + bj0;
        float v1 = (lm < 8) ? (acc1[reg] + bj1) : -INFINITY;
        float mx = fmaxf(v0, v1);
#pragma unroll
        for (int off = 16; off >= 1; off >>= 1) mx = fmaxf(mx, __shfl_xor(mx, off, 64));
        float s = __expf(v0 - mx) + ((lm < 8) ? __expf(v1 - mx) : 0.f);
#pragma unroll
        for (int off = 16; off >= 1; off >>= 1) s += __shfl_xor(s, off, 64);
        float ls = __logf(s) + mx;
        int gm = wm0 + row;
        if (gm < N_NODES) {
            out[(size_t)gm * 40 + lm] = v0 - ls;
            if (lm < 8) out[(size_t)gm * 40 + 32 + lm] = v1 - ls;
        }
    }
}

extern "C" void kernel_launch(void* const* d_in, const int* in_sizes, int n_in,
                              void* d_out, int out_size, void* d_ws, size_t ws_size,
                              hipStream_t stream) {
    const float* x   = (const float*)d_in[0];
    const int*   ei  = (const int*)  d_in[1];
    const float* t1w = (const float*)d_in[2];
    const float* t1b = (const float*)d_in[3];
    const float* gw  = (const float*)d_in[4];
    const float* gb  = (const float*)d_in[5];
    const float* w2  = (const float*)d_in[6];
    const float* b2  = (const float*)d_in[7];
    float* out = (float*)d_out;

    char* p = (char*)d_ws;
    int*    colptr   = (int*)p;    p += (size_t)(N_NODES + 64) * 4;
    int*    partials = (int*)p;    p += 256 * 4;
    float*  nd       = (float*)p;  p += (size_t)N_NODES * 4;
    int*    cnt      = (int*)p;    p += (size_t)N_NODES * 4;
    float*  dcb0     = (float*)p;  p += (size_t)N_NODES * 4;
    float*  dcb1     = (float*)p;  p += (size_t)N_NODES * 4;
    float2* dn0      = (float2*)p; p += (size_t)N_NODES * 8;
    float2* dn1      = (float2*)p; p += (size_t)N_NODES * 8;
    int*    csr      = (int*)p;    p += (size_t)N_EDGES * 4;
    _Float16* wh     = (_Float16*)p; p += (size_t)HIDDEN * 512 * 2;
    _Float16* w2h    = (_Float16*)p; p += (size_t)64 * HIDDEN * 2;  // zero-padded 64x128 f16 W2
    // transient region (dead after k_scatter2) overlaps hb0..hb2 (25.6 + 12.8 = 38.4 MB = 3x12.8):
    char* q = p;
    unsigned int*  part   = (unsigned int*)q;                                        // 25.6 MB
    unsigned char* cntpre = (unsigned char*)(q + (size_t)2 * NCHUNK * NWORDS * 4);   // 12.8 MB (u8)
    // h region (written from k_gemm1 onward), all f16
    __half2* hb0 = (__half2*)p; p += (size_t)N_NODES * 64 * 4;   // 12.8 MB (layer-0 h = raw)
    __half2* hb1 = (__half2*)p; p += (size_t)N_NODES * 64 * 4;   // 12.8 MB (layer-1 h)
    __half2* hb2 = (__half2*)p; p += (size_t)N_NODES * 64 * 4;   // 12.8 MB (layer-2 h)

    // ---- graph preprocessing (zero global atomics) ----
    k_hist<<<2 * NCHUNK, 256, 0, stream>>>(ei, part);
    k_reduce<<<(NWORDS + 255) / 256, 256, 0, stream>>>(part, nd, cnt, cntpre);
    int nb = (N_NODES + 1023) / 1024;   // 49
    k_scan_a<<<nb, 256, 0, stream>>>(cnt, colptr, partials);
    k_scan_b<<<1, 64, 0, stream>>>(partials, colptr, nb);
    k_scan_c<<<(N_NODES + 255) / 256, 256, 0, stream>>>(colptr, partials);
    k_scatter2<<<NCHUNK, 256, 0, stream>>>(ei, colptr, cntpre, csr);

    // ---- dense pipeline (f16 h-state throughout) ----
    k_cvt<<<(16384 + 255) / 256, 256, 0, stream>>>((const float4*)t1w, (__half2*)wh, 16384);
    k_cvtw<<<8, 256, 0, stream>>>((const float4*)w2, (__half2*)w2h, 40 * HIDDEN / 4, 64 * HIDDEN / 4);
    k_gemm1<<<(N_NODES + 63) / 64, 256, 0, stream>>>(x, wh, t1b, (_Float16*)hb0);

    k_dot<<<(N_NODES + 3) / 4, 256, 0, stream>>>(hb0, gw, gb, nd, 0, dn0, dcb0);
    // layer-1 propagation: inline gate (reads dn0/dcb0) + fused layer-1 gate dot (writes dn1/dcb1)
    k_prop<<<(N_NODES + 3) / 4, 256, 0, stream>>>(hb0, hb0, colptr, csr, dn0, dcb0, nd,
                                                  gw + 256, gb + 1, dn1, dcb1, hb1);
    // layer-2 propagation: inline gate (reads dn1/dcb1), no epilogue dot
    k_prop<<<(N_NODES + 3) / 4, 256, 0, stream>>>(hb1, hb0, colptr, csr, dn1, dcb1, nd,
                                                  (const float*)nullptr, (const float*)nullptr,
                                                  (float2*)nullptr, (float*)nullptr, hb2);

    k_out<<<(N_NODES + 127) / 128, 256, 0, stream>>>((const _Float16*)hb2, w2h, b2, out);
}

// Round 11
// 448.012 us; speedup vs baseline: 1.0345x; 1.0345x over previous
//
#include <hip/hip_runtime.h>
#include <hip/hip_bf16.h>
#include <hip/hip_fp16.h>

#define N_NODES 50000
#define N_EDGES 1600000
#define HIDDEN  128
#define EPS_C   0.3f
#define NWORDS  12500      // 50000 nodes, 4 u8 counters per u32 word
#define CHUNK   6250       // edges per histogram block; 256 chunks = 1.6M
#define NCHUNK  256

typedef _Float16 f16x8 __attribute__((ext_vector_type(8)));
typedef _Float16 f16x4 __attribute__((ext_vector_type(4)));
typedef float    f32x16 __attribute__((ext_vector_type(16)));

// ---------------- per-chunk LDS histograms (u8-packed), zero global atomics ----------------
// grid 512: blocks 0..255 count rows (deg), 256..511 count cols (cnt)
__global__ __launch_bounds__(256) void k_hist(const int* __restrict__ ei, unsigned int* __restrict__ part) {
    __shared__ unsigned int hist[NWORDS];   // 50 KB
    int b = blockIdx.x;
    int type  = b >> 8;
    int chunk = b & 255;
    const int* src = ei + (size_t)type * N_EDGES + (size_t)chunk * CHUNK;
    for (int i = threadIdx.x; i < NWORDS; i += 256) hist[i] = 0;
    __syncthreads();
    for (int i = threadIdx.x; i < CHUNK; i += 256) {
        int v = src[i];
        atomicAdd(&hist[v >> 2], 1u << ((v & 3) * 8));
    }
    __syncthreads();
    unsigned int* dst = part + ((size_t)type * NCHUNK + chunk) * NWORDS;
    for (int i = threadIdx.x; i < NWORDS; i += 256) dst[i] = hist[i];
}

// ---------------- reduce partials -> nd, cnt, and per-(chunk,col) u8 exclusive prefix ----------------
__global__ __launch_bounds__(256) void k_reduce(const unsigned int* __restrict__ part,
                                                float* __restrict__ nd, int* __restrict__ cnt,
                                                unsigned char* __restrict__ cntpre) {
    int w = blockIdx.x * 256 + threadIdx.x;
    if (w >= NWORDS) return;
    // deg (rows)
    unsigned int s0 = 0, s1 = 0, s2 = 0, s3 = 0;
    const unsigned int* dp = part + w;
    for (int b = 0; b < NCHUNK; ++b) {
        unsigned int v = dp[(size_t)b * NWORDS];
        s0 += v & 255u; s1 += (v >> 8) & 255u; s2 += (v >> 16) & 255u; s3 += v >> 24;
    }
    nd[4 * w + 0] = rsqrtf(fmaxf((float)s0, 1.f));
    nd[4 * w + 1] = rsqrtf(fmaxf((float)s1, 1.f));
    nd[4 * w + 2] = rsqrtf(fmaxf((float)s2, 1.f));
    nd[4 * w + 3] = rsqrtf(fmaxf((float)s3, 1.f));
    // cnt (cols) + u8 exclusive prefix per chunk (per-chunk per-node count << 255)
    const unsigned int* cp = part + (size_t)NCHUNK * NWORDS + w;
    unsigned int r0 = 0, r1 = 0, r2 = 0, r3 = 0;
    for (int b = 0; b < NCHUNK; ++b) {
        size_t o = (size_t)b * N_NODES + 4 * w;
        *(uchar4*)&cntpre[o] = make_uchar4((unsigned char)r0, (unsigned char)r1,
                                           (unsigned char)r2, (unsigned char)r3);
        unsigned int v = cp[(size_t)b * NWORDS];
        r0 += v & 255u; r1 += (v >> 8) & 255u; r2 += (v >> 16) & 255u; r3 += v >> 24;
    }
    cnt[4 * w + 0] = (int)r0;
    cnt[4 * w + 1] = (int)r1;
    cnt[4 * w + 2] = (int)r2;
    cnt[4 * w + 3] = (int)r3;
}

// ---------------- 3-kernel exclusive scan of cnt -> colptr ----------------
__global__ __launch_bounds__(256) void k_scan_a(const int* __restrict__ cnt,
                                                int* __restrict__ out, int* __restrict__ partials) {
    __shared__ int sh[256];
    int t = threadIdx.x;
    int base = blockIdx.x * 1024 + t * 4;
    int v0 = (base + 0 < N_NODES) ? cnt[base + 0] : 0;
    int v1 = (base + 1 < N_NODES) ? cnt[base + 1] : 0;
    int v2 = (base + 2 < N_NODES) ? cnt[base + 2] : 0;
    int v3 = (base + 3 < N_NODES) ? cnt[base + 3] : 0;
    int s = v0 + v1 + v2 + v3;
    sh[t] = s;
    __syncthreads();
    for (int off = 1; off < 256; off <<= 1) {
        int add = (t >= off) ? sh[t - off] : 0;
        __syncthreads();
        sh[t] += add;
        __syncthreads();
    }
    int excl = sh[t] - s;
    if (t == 255) partials[blockIdx.x] = sh[255];
    if (base + 0 < N_NODES) out[base + 0] = excl;
    if (base + 1 < N_NODES) out[base + 1] = excl + v0;
    if (base + 2 < N_NODES) out[base + 2] = excl + v0 + v1;
    if (base + 3 < N_NODES) out[base + 3] = excl + v0 + v1 + v2;
}

__global__ void k_scan_b(int* partials, int* colptr, int nb) {
    if (threadIdx.x == 0 && blockIdx.x == 0) {
        int run = 0;
        for (int i = 0; i < nb; ++i) { int t = partials[i]; partials[i] = run; run += t; }
        colptr[N_NODES] = run;   // == E
    }
}

__global__ void k_scan_c(int* __restrict__ colptr, const int* __restrict__ partials) {
    int i = blockIdx.x * blockDim.x + threadIdx.x;
    if (i >= N_NODES) return;
    colptr[i] += partials[i >> 10];
}

// ---------------- scatter via LDS rank, zero global atomics ----------------
__global__ __launch_bounds__(256) void k_scatter2(const int* __restrict__ ei, const int* __restrict__ colptr,
                                                  const unsigned char* __restrict__ cntpre,
                                                  int* __restrict__ csr) {
    __shared__ unsigned int rank[NWORDS];   // 50 KB
    int b = blockIdx.x;
    for (int i = threadIdx.x; i < NWORDS; i += 256) rank[i] = 0;
    __syncthreads();
    const int* rs = ei + (size_t)b * CHUNK;
    const int* cs = ei + N_EDGES + (size_t)b * CHUNK;
    const unsigned char* pre = cntpre + (size_t)b * N_NODES;
    for (int i = threadIdx.x; i < CHUNK; i += 256) {
        int r = rs[i];
        int c = cs[i];
        unsigned int old = atomicAdd(&rank[c >> 2], 1u << ((c & 3) * 8));
        unsigned int lr = (old >> ((c & 3) * 8)) & 255u;
        int pos = colptr[c] + (int)pre[c] + (int)lr;
        csr[pos] = r;
    }
}

// ---------------- fp32 -> fp16 convert (n4 = count of float4) ----------------
__global__ void k_cvt(const float4* __restrict__ src, __half2* __restrict__ dst, int n4) {
    int i = blockIdx.x * 256 + threadIdx.x;
    if (i >= n4) return;
    float4 v = src[i];
    dst[2 * i]     = __floats2half2_rn(v.x, v.y);
    dst[2 * i + 1] = __floats2half2_rn(v.z, v.w);
}

// ---------------- fp32 -> fp16 convert with zero-padding past n4src ----------------
__global__ void k_cvtw(const float4* __restrict__ src, __half2* __restrict__ dst, int n4src, int n4tot) {
    int i = blockIdx.x * 256 + threadIdx.x;
    if (i >= n4tot) return;
    if (i < n4src) {
        float4 v = src[i];
        dst[2 * i]     = __floats2half2_rn(v.x, v.y);
        dst[2 * i + 1] = __floats2half2_rn(v.z, v.w);
    } else {
        __half2 z = __floats2half2_rn(0.f, 0.f);
        dst[2 * i]     = z;
        dst[2 * i + 1] = z;
    }
}

// ---------------- GEMM1: h = relu(x @ W1^T + b1), LDS-staged fp16 MFMA, f16-only output ----------------
__global__ __launch_bounds__(256) void k_gemm1(const float* __restrict__ x, const _Float16* __restrict__ wh,
                                               const float* __restrict__ bias, _Float16* __restrict__ hb) {
    __shared__ _Float16 As[64 * 64];    // 8 KB, swizzled
    __shared__ _Float16 Bs[128 * 64];   // 16 KB, swizzled
    int t = threadIdx.x;
    int wave = t >> 6;
    int lane = t & 63;
    int lm   = lane & 31;
    int half = lane >> 5;
    int mstrip = wave & 1;
    int nstrip = wave >> 1;

    int m0  = blockIdx.x * 64;
    int wm0 = m0 + mstrip * 32;     // wave's M base
    int n0  = nstrip * 64;          // wave's N base

    int aidx[4], arow[4], ac4[4];
    int bidx, brow[4], bg[4];
#pragma unroll
    for (int i = 0; i < 4; ++i) {
        aidx[i] = i * 256 + t;
        arow[i] = aidx[i] >> 4;
        ac4[i]  = aidx[i] & 15;
        bidx    = i * 256 + t;
        brow[i] = bidx >> 3;
        bg[i]   = bidx & 7;
    }

    float4 pa[4];
    f16x8  pb[4];
#define LOAD_TILES(K0)                                                                    \
    {                                                                                     \
        _Pragma("unroll")                                                                 \
        for (int i = 0; i < 4; ++i) {                                                     \
            int gr = m0 + arow[i]; if (gr >= N_NODES) gr = N_NODES - 1;                   \
            pa[i] = *(const float4*)(x + (size_t)gr * 512 + (K0) + ac4[i] * 4);           \
            pb[i] = *(const f16x8*)(wh + (size_t)brow[i] * 512 + (K0) + bg[i] * 8);       \
        }                                                                                 \
    }

    f32x16 acc0, acc1;
#pragma unroll
    for (int i = 0; i < 16; ++i) { acc0[i] = 0.f; acc1[i] = 0.f; }

    int ar = mstrip * 32 + lm;
    int brA = n0 + lm;
    int brB = n0 + 32 + lm;

    LOAD_TILES(0);
    for (int k0 = 0; k0 < 512; k0 += 64) {
#pragma unroll
        for (int i = 0; i < 4; ++i) {
            f16x4 a;
            a[0] = (_Float16)pa[i].x; a[1] = (_Float16)pa[i].y;
            a[2] = (_Float16)pa[i].z; a[3] = (_Float16)pa[i].w;
            int g = ac4[i] >> 1;
            *(f16x4*)&As[arow[i] * 64 + (((g ^ (arow[i] & 7)) << 3)) + (ac4[i] & 1) * 4] = a;
            *(f16x8*)&Bs[brow[i] * 64 + ((bg[i] ^ (brow[i] & 7)) << 3)] = pb[i];
        }
        __syncthreads();
        if (k0 + 64 < 512) LOAD_TILES(k0 + 64);   // prefetch overlaps compute
#pragma unroll
        for (int kk = 0; kk < 4; ++kk) {
            int ag = kk * 2 + half;
            f16x8 av  = *(const f16x8*)&As[ar  * 64 + ((ag ^ (ar  & 7)) << 3)];
            f16x8 bv0 = *(const f16x8*)&Bs[brA * 64 + ((ag ^ (brA & 7)) << 3)];
            f16x8 bv1 = *(const f16x8*)&Bs[brB * 64 + ((ag ^ (brA & 7)) << 3)];
            acc0 = __builtin_amdgcn_mfma_f32_32x32x16_f16(av, bv0, acc0, 0, 0, 0);
            acc1 = __builtin_amdgcn_mfma_f32_32x32x16_f16(av, bv1, acc1, 0, 0, 0);
        }
        __syncthreads();
    }
#undef LOAD_TILES

    float bs0 = bias[n0 + lm];
    float bs1 = bias[n0 + 32 + lm];
#pragma unroll
    for (int reg = 0; reg < 16; ++reg) {
        int row = (reg & 3) + 8 * (reg >> 2) + 4 * half;
        int gm = wm0 + row;
        if (gm < N_NODES) {
            float v0 = fmaxf(acc0[reg] + bs0, 0.f);
            float v1 = fmaxf(acc1[reg] + bs1, 0.f);
            hb[(size_t)gm * HIDDEN + n0 + lm]      = (_Float16)v0;
            hb[(size_t)gm * HIDDEN + n0 + 32 + lm] = (_Float16)v1;
        }
    }
}

// ---------------- per-node gate dots (layer 0): dn = {h.w_r, nd}, dcb = h.w_c + gb ----------------
__global__ __launch_bounds__(256) void k_dot(const __half2* __restrict__ hb, const float* __restrict__ gw,
                                             const float* __restrict__ gb, const float* __restrict__ nd,
                                             int layer, float2* __restrict__ dn, float* __restrict__ dcb) {
    int node = blockIdx.x * 4 + (threadIdx.x >> 6);
    int lane = threadIdx.x & 63;
    if (node >= N_NODES) return;
    float2 wr = ((const float2*)(gw + layer * 256))[lane];
    float2 wc = ((const float2*)(gw + layer * 256 + 128))[lane];
    float2 hc = __half22float2(hb[(size_t)node * 64 + lane]);
    float a = hc.x * wr.x + hc.y * wr.y;
    float b = hc.x * wc.x + hc.y * wc.y;
#pragma unroll
    for (int off = 32; off >= 1; off >>= 1) {
        a += __shfl_xor(a, off, 64);
        b += __shfl_xor(b, off, 64);
    }
    if (lane == 0) {
        dn[node]  = make_float2(a, nd[node]);
        dcb[node] = b + gb[layer];
    }
}

// ---------------- propagation with LDS-batch fused gate: wave per node (round-8 body) ----------------
// Per 64-edge batch: lane-parallel gate (coalesced csr load + dn gather + tanh, exp amortized
// across 64 lanes) stashed into per-wave LDS, then an 8-wide inner loop with uniform-address
// ds_read broadcasts. No warr round-trip, csr read once. dn/dcb double-buffered across layers.
__global__ __launch_bounds__(256) void k_prop(const __half2* __restrict__ hb, const __half2* __restrict__ rawh,
                                              const int* __restrict__ colptr, const int* __restrict__ csr,
                                              const float2* __restrict__ dn_in, const float* __restrict__ dcb_in,
                                              const float* __restrict__ nd,
                                              const float* __restrict__ gw_next, const float* __restrict__ gb_next,
                                              float2* __restrict__ dn_out, float* __restrict__ dcb_out,
                                              __half2* __restrict__ hbn) {
    __shared__ int   lrs[4][64];
    __shared__ float lws[4][64];
    int lane = threadIdx.x & 63;
    int wid  = threadIdx.x >> 6;
    // wave-uniform node/beg/end in SGPRs
    int node = __builtin_amdgcn_readfirstlane(blockIdx.x * 4 + wid);
    int beg = __builtin_amdgcn_readfirstlane(colptr[node]);
    int end = __builtin_amdgcn_readfirstlane(colptr[node + 1]);
    float dc = dcb_in[node];
    float acc0 = 0.f, acc1 = 0.f;
    for (int base = beg; base < end; base += 64) {
        // ---- lane-parallel gate phase for this 64-edge batch ----
        int e  = base + lane;
        int ec = (e < end) ? e : (end - 1);
        int r  = csr[ec];                       // coalesced
        float2 v = dn_in[r];                    // {dot_r, nd[r]} gather (400 KB, L2-resident)
        float xx = v.x + dc;
        float t = __expf(2.0f * xx);            // saturates to inf / 0, no NaN below
        float g = 1.0f - 2.0f / (t + 1.0f);     // == tanh(xx)
        float w = (e < end) ? g * v.y : 0.f;    // zero-pad invalid lanes -> fma no-op
        lrs[wid][lane] = r;
        lws[wid][lane] = w;                     // same-wave producer/consumer: lgkmcnt only
        int m = end - base; if (m > 64) m = 64;
        int mm = (m + 7) & ~7;                  // padded entries have w=0, r clamped valid
        // ---- 8-wide gather/accumulate, uniform ds_read broadcasts ----
        for (int j = 0; j < mm; j += 8) {
            int r0 = lrs[wid][j + 0], r1 = lrs[wid][j + 1], r2 = lrs[wid][j + 2], r3 = lrs[wid][j + 3];
            int r4 = lrs[wid][j + 4], r5 = lrs[wid][j + 5], r6 = lrs[wid][j + 6], r7 = lrs[wid][j + 7];
            float w0 = lws[wid][j + 0], w1 = lws[wid][j + 1], w2 = lws[wid][j + 2], w3 = lws[wid][j + 3];
            float w4 = lws[wid][j + 4], w5 = lws[wid][j + 5], w6 = lws[wid][j + 6], w7 = lws[wid][j + 7];
            __half2 v0 = hb[(size_t)r0 * 64 + lane];
            __half2 v1 = hb[(size_t)r1 * 64 + lane];
            __half2 v2 = hb[(size_t)r2 * 64 + lane];
            __half2 v3 = hb[(size_t)r3 * 64 + lane];
            __half2 v4 = hb[(size_t)r4 * 64 + lane];
            __half2 v5 = hb[(size_t)r5 * 64 + lane];
            __half2 v6 = hb[(size_t)r6 * 64 + lane];
            __half2 v7 = hb[(size_t)r7 * 64 + lane];
            acc0 = fmaf(w0, __low2float(v0), acc0);  acc1 = fmaf(w0, __high2float(v0), acc1);
            acc0 = fmaf(w1, __low2float(v1), acc0);  acc1 = fmaf(w1, __high2float(v1), acc1);
            acc0 = fmaf(w2, __low2float(v2), acc0);  acc1 = fmaf(w2, __high2float(v2), acc1);
            acc0 = fmaf(w3, __low2float(v3), acc0);  acc1 = fmaf(w3, __high2float(v3), acc1);
            acc0 = fmaf(w4, __low2float(v4), acc0);  acc1 = fmaf(w4, __high2float(v4), acc1);
            acc0 = fmaf(w5, __low2float(v5), acc0);  acc1 = fmaf(w5, __high2float(v5), acc1);
            acc0 = fmaf(w6, __low2float(v6), acc0);  acc1 = fmaf(w6, __high2float(v6), acc1);
            acc0 = fmaf(w7, __low2float(v7), acc0);  acc1 = fmaf(w7, __high2float(v7), acc1);
        }
    }
    float ndc = nd[node];
    float2 rw = __half22float2(rawh[(size_t)node * 64 + lane]);
    float2 o;
    o.x = fmaf(EPS_C, rw.x, ndc * acc0);
    o.y = fmaf(EPS_C, rw.y, ndc * acc1);
    hbn[(size_t)node * 64 + lane] = __floats2half2_rn(o.x, o.y);
    if (gw_next) {
        // fused next-layer gate dot -> double-buffered dn_out/dcb_out
        float2 wr = ((const float2*)gw_next)[lane];
        float2 wc = ((const float2*)(gw_next + 128))[lane];
        float a = o.x * wr.x + o.y * wr.y;
        float b = o.x * wc.x + o.y * wc.y;
#pragma unroll
        for (int off = 32; off >= 1; off >>= 1) {
            a += __shfl_xor(a, off, 64);
            b += __shfl_xor(b, off, 64);
        }
        if (lane == 0) {
            dn_out[node]  = make_float2(a, ndc);
            dcb_out[node] = b + gb_next[0];
        }
    }
}

// ---------------- output: logits = h @ W2^T + b2 via MFMA, log_softmax in epilogue ----------------
__global__ __launch_bounds__(256) void k_out(const _Float16* __restrict__ h16, const _Float16* __restrict__ w2h,
                                             const float* __restrict__ b2, float* __restrict__ out) {
    int wave = threadIdx.x >> 6;
    int lane = threadIdx.x & 63;
    int lm   = lane & 31;
    int half = lane >> 5;

    int wm0 = blockIdx.x * 128 + wave * 32;
    int m   = wm0 + lm;
    int mc  = (m < N_NODES) ? m : (N_NODES - 1);

    const _Float16* arow  = h16 + (size_t)mc * HIDDEN + half * 8;
    const _Float16* brow0 = w2h + (size_t)lm * HIDDEN + half * 8;
    const _Float16* brow1 = w2h + (size_t)(32 + lm) * HIDDEN + half * 8;

    f32x16 acc0, acc1;
#pragma unroll
    for (int i = 0; i < 16; ++i) { acc0[i] = 0.f; acc1[i] = 0.f; }

#pragma unroll
    for (int k0 = 0; k0 < 128; k0 += 16) {
        f16x8 av = *(const f16x8*)(arow  + k0);
        f16x8 b0 = *(const f16x8*)(brow0 + k0);
        f16x8 b1 = *(const f16x8*)(brow1 + k0);
        acc0 = __builtin_amdgcn_mfma_f32_32x32x16_f16(av, b0, acc0, 0, 0, 0);
        acc1 = __builtin_amdgcn_mfma_f32_32x32x16_f16(av, b1, acc1, 0, 0, 0);
    }

    float bj0 = b2[lm];
    float bj1 = (lm < 8) ? b2[32 + lm] : 0.f;

#pragma unroll
    for (int reg = 0; reg < 16; ++reg) {
        int row = (reg & 3) + 8 * (reg >> 2) + 4 * half;
        float v0 = acc0[reg] + bj0;
        float v1 = (lm < 8) ? (acc1[reg] + bj1) : -INFINITY;
        float mx = fmaxf(v0, v1);
#pragma unroll
        for (int off = 16; off >= 1; off >>= 1) mx = fmaxf(mx, __shfl_xor(mx, off, 64));
        float s = __expf(v0 - mx) + ((lm < 8) ? __expf(v1 - mx) : 0.f);
#pragma unroll
        for (int off = 16; off >= 1; off >>= 1) s += __shfl_xor(s, off, 64);
        float ls = __logf(s) + mx;
        int gm = wm0 + row;
        if (gm < N_NODES) {
            out[(size_t)gm * 40 + lm] = v0 - ls;
            if (lm < 8) out[(size_t)gm * 40 + 32 + lm] = v1 - ls;
        }
    }
}

extern "C" void kernel_launch(void* const* d_in, const int* in_sizes, int n_in,
                              void* d_out, int out_size, void* d_ws, size_t ws_size,
                              hipStream_t stream) {
    const float* x   = (const float*)d_in[0];
    const int*   ei  = (const int*)  d_in[1];
    const float* t1w = (const float*)d_in[2];
    const float* t1b = (const float*)d_in[3];
    const float* gw  = (const float*)d_in[4];
    const float* gb  = (const float*)d_in[5];
    const float* w2  = (const float*)d_in[6];
    const float* b2  = (const float*)d_in[7];
    float* out = (float*)d_out;

    char* p = (char*)d_ws;
    int*    colptr   = (int*)p;    p += (size_t)(N_NODES + 64) * 4;
    int*    partials = (int*)p;    p += 256 * 4;
    float*  nd       = (float*)p;  p += (size_t)N_NODES * 4;
    int*    cnt      = (int*)p;    p += (size_t)N_NODES * 4;
    float*  dcb0     = (float*)p;  p += (size_t)N_NODES * 4;
    float*  dcb1     = (float*)p;  p += (size_t)N_NODES * 4;
    float2* dn0      = (float2*)p; p += (size_t)N_NODES * 8;
    float2* dn1      = (float2*)p; p += (size_t)N_NODES * 8;
    int*    csr      = (int*)p;    p += (size_t)N_EDGES * 4;
    _Float16* wh     = (_Float16*)p; p += (size_t)HIDDEN * 512 * 2;
    _Float16* w2h    = (_Float16*)p; p += (size_t)64 * HIDDEN * 2;  // zero-padded 64x128 f16 W2
    // transient region (dead after k_scatter2) overlaps hb0..hb2 (25.6 + 12.8 = 38.4 MB = 3x12.8):
    char* q = p;
    unsigned int*  part   = (unsigned int*)q;                                        // 25.6 MB
    unsigned char* cntpre = (unsigned char*)(q + (size_t)2 * NCHUNK * NWORDS * 4);   // 12.8 MB (u8)
    // h region (written from k_gemm1 onward), all f16
    __half2* hb0 = (__half2*)p; p += (size_t)N_NODES * 64 * 4;   // 12.8 MB (layer-0 h = raw)
    __half2* hb1 = (__half2*)p; p += (size_t)N_NODES * 64 * 4;   // 12.8 MB (layer-1 h)
    __half2* hb2 = (__half2*)p; p += (size_t)N_NODES * 64 * 4;   // 12.8 MB (layer-2 h)

    // ---- graph preprocessing (zero global atomics) ----
    k_hist<<<2 * NCHUNK, 256, 0, stream>>>(ei, part);
    k_reduce<<<(NWORDS + 255) / 256, 256, 0, stream>>>(part, nd, cnt, cntpre);
    int nb = (N_NODES + 1023) / 1024;   // 49
    k_scan_a<<<nb, 256, 0, stream>>>(cnt, colptr, partials);
    k_scan_b<<<1, 64, 0, stream>>>(partials, colptr, nb);
    k_scan_c<<<(N_NODES + 255) / 256, 256, 0, stream>>>(colptr, partials);
    k_scatter2<<<NCHUNK, 256, 0, stream>>>(ei, colptr, cntpre, csr);

    // ---- dense pipeline (f16 h-state throughout) ----
    k_cvt<<<(16384 + 255) / 256, 256, 0, stream>>>((const float4*)t1w, (__half2*)wh, 16384);
    k_cvtw<<<8, 256, 0, stream>>>((const float4*)w2, (__half2*)w2h, 40 * HIDDEN / 4, 64 * HIDDEN / 4);
    k_gemm1<<<(N_NODES + 63) / 64, 256, 0, stream>>>(x, wh, t1b, (_Float16*)hb0);

    k_dot<<<(N_NODES + 3) / 4, 256, 0, stream>>>(hb0, gw, gb, nd, 0, dn0, dcb0);
    // layer-1 propagation: LDS-batch gate (reads dn0/dcb0) + fused layer-1 gate dot (writes dn1/dcb1)
    k_prop<<<(N_NODES + 3) / 4, 256, 0, stream>>>(hb0, hb0, colptr, csr, dn0, dcb0, nd,
                                                  gw + 256, gb + 1, dn1, dcb1, hb1);
    // layer-2 propagation: LDS-batch gate (reads dn1/dcb1), no epilogue dot
    k_prop<<<(N_NODES + 3) / 4, 256, 0, stream>>>(hb1, hb0, colptr, csr, dn1, dcb1, nd,
                                                  (const float*)nullptr, (const float*)nullptr,
                                                  (float2*)nullptr, (float*)nullptr, hb2);

    k_out<<<(N_NODES + 127) / 128, 256, 0, stream>>>((const _Float16*)hb2, w2h, b2, out);
}